// Round 3
// baseline (709.692 us; speedup 1.0000x reference)
//
#include <hip/hip_runtime.h>
#include <hip/hip_bf16.h>

typedef __attribute__((ext_vector_type(8))) short bf16x8;
typedef __attribute__((ext_vector_type(4))) short short4v;
typedef __attribute__((ext_vector_type(4))) float f32x4;

#define TAU_INV 2.0f

__device__ __forceinline__ short f2bf(float f) {
  unsigned u = __float_as_uint(f);
  u += 0x7fffu + ((u >> 16) & 1u);
  return (short)(u >> 16);
}
__device__ __forceinline__ float bf2f(short s) {
  return __uint_as_float(((unsigned)(unsigned short)s) << 16);
}

// ---------------- weight prep: concat-transpose to [c][k] bf16 ----------------
// t_cat[2688][384]: cols 0..767 = W_state, 768..1535 = W_inj,
//                   1536..1919 = W_ga, 1920..2303 = W_gb, 2304..2687 = W_s1
// t_out[384][768] = W_out^T
__global__ __launch_bounds__(256) void prep_weights(
    const float* __restrict__ w_state, const float* __restrict__ w_inj,
    const float* __restrict__ w_ga, const float* __restrict__ w_gb,
    const float* __restrict__ w_s1, const float* __restrict__ w_out,
    short* __restrict__ t_cat, short* __restrict__ t_out)
{
  int idx = blockIdx.x * 256 + threadIdx.x;
  const int NCAT = 2688 * 384;
  if (idx < NCAT) {
    int c = idx / 384, k = idx - c * 384;
    float v;
    if (c < 768)        v = w_state[k * 768 + c];
    else if (c < 1536)  v = w_inj[k * 768 + (c - 768)];
    else if (c < 1920)  v = w_ga[k * 384 + (c - 1536)];
    else if (c < 2304)  v = w_gb[k * 384 + (c - 1920)];
    else                v = w_s1[k * 384 + (c - 2304)];
    t_cat[idx] = f2bf(v);
  } else {
    int j = idx - NCAT;           // < 384*768
    int c = j / 768, k = j - c * 768;
    t_out[c * 768 + k] = f2bf(w_out[k * 384 + c]);
  }
}

// ---------------- x -> bf16 once ----------------
__global__ __launch_bounds__(256) void prep_x(
    const float* __restrict__ X, short* __restrict__ Xb)
{
  int t = blockIdx.x * 256 + threadIdx.x;   // 1572864 threads, 8 elems each
  int base = t * 8;
  float4 a = *(const float4*)(X + base);
  float4 b = *(const float4*)(X + base + 4);
  bf16x8 s;
  s[0] = f2bf(a.x); s[1] = f2bf(a.y); s[2] = f2bf(a.z); s[3] = f2bf(a.w);
  s[4] = f2bf(b.x); s[5] = f2bf(b.y); s[6] = f2bf(b.z); s[7] = f2bf(b.w);
  *(bf16x8*)(Xb + base) = s;
}

// ---------------- fused GEMM over x: all 5 projections in one pass ----------------
__global__ __launch_bounds__(256) void gemm_fused(
    const short* __restrict__ Xb, const short* __restrict__ Wt,
    const float* __restrict__ b_ga, const float* __restrict__ b_gb,
    const float* __restrict__ b_s1,
    short* __restrict__ ug, short* __restrict__ vg,
    short* __restrict__ xug, short* __restrict__ xvg,
    short* __restrict__ gag, short* __restrict__ gbg,
    short* __restrict__ s1)
{
  __shared__ short As[128 * 72];
  __shared__ short Bs[128 * 72];
  const int tid = threadIdx.x;
  const int lane = tid & 63;
  const int wv = tid >> 6;
  const int wr = wv >> 1, wc = wv & 1;
  const int m0 = blockIdx.x * 128, c0 = blockIdx.y * 128;
  const int l15 = lane & 15, l4 = lane >> 4;
  f32x4 acc[4][4] = {};
  for (int k0 = 0; k0 < 384; k0 += 64) {
    __syncthreads();
#pragma unroll
    for (int i = 0; i < 4; ++i) {
      int h = tid + i * 256;
      int m = h >> 3, kc = (h & 7) * 8;
      bf16x8 xv = *(const bf16x8*)(Xb + (m0 + m) * 384 + k0 + kc);
      *(bf16x8*)(As + m * 72 + kc) = xv;
    }
#pragma unroll
    for (int i = 0; i < 4; ++i) {
      int h = tid + i * 256;
      int c = h >> 3, kc = (h & 7) * 8;
      bf16x8 wvv = *(const bf16x8*)(Wt + (c0 + c) * 384 + k0 + kc);
      *(bf16x8*)(Bs + c * 72 + kc) = wvv;
    }
    __syncthreads();
#pragma unroll
    for (int kk = 0; kk < 2; ++kk) {
      bf16x8 af[4], bfv[4];
#pragma unroll
      for (int f = 0; f < 4; ++f) {
        af[f]  = *(const bf16x8*)(As + (wr * 64 + f * 16 + l15) * 72 + kk * 32 + l4 * 8);
        bfv[f] = *(const bf16x8*)(Bs + (wc * 64 + f * 16 + l15) * 72 + kk * 32 + l4 * 8);
      }
#pragma unroll
      for (int i = 0; i < 4; ++i)
#pragma unroll
        for (int j = 0; j < 4; ++j)
          acc[i][j] = __builtin_amdgcn_mfma_f32_16x16x32_bf16(af[i], bfv[j], acc[i][j], 0, 0, 0);
    }
  }
#pragma unroll
  for (int i = 0; i < 4; ++i) {
#pragma unroll
    for (int j = 0; j < 4; ++j) {
      const int c = c0 + wc * 64 + j * 16 + l15;
      const int mb = m0 + wr * 64 + i * 16 + l4 * 4;
      const int b = mb >> 12, n = mb & 4095;
      f32x4 v = acc[i][j];
      if (c < 1536) {               // state / inj -> grid split stores
        int cc = (c >= 768) ? (c - 768) : c;
        short* base;
        if (c < 768) base = (cc < 384) ? ug : vg;
        else         base = (cc < 384) ? xug : xvg;
        int plane = (cc >= 384) ? (cc - 384) : cc;
        short4v s;
        s[0] = f2bf(v[0]); s[1] = f2bf(v[1]); s[2] = f2bf(v[2]); s[3] = f2bf(v[3]);
        *(short4v*)(base + (b * 384 + plane) * 4096 + n) = s;
      } else if (c < 2304) {        // gates: sigmoid
        const float* bias = (c < 1920) ? b_ga : b_gb;
        short* base = (c < 1920) ? gag : gbg;
        int plane = (c < 1920) ? (c - 1536) : (c - 1920);
        float bb = bias[plane];
        short4v s;
#pragma unroll
        for (int r = 0; r < 4; ++r) {
          float t = v[r] + bb;
          s[r] = f2bf(1.f / (1.f + __expf(-t)));
        }
        *(short4v*)(base + (b * 384 + plane) * 4096 + n) = s;
      } else {                      // s1: silu, natural [m][c] layout
        int plane = c - 2304;
        float bb = b_s1[plane];
#pragma unroll
        for (int r = 0; r < 4; ++r) {
          float t = v[r] + bb;
          float sg = 1.f / (1.f + __expf(-t));
          s1[(mb + r) * 384 + plane] = f2bf(t * sg);
        }
      }
    }
  }
}

// ---------------- psi: s1 @ W_stream2 + b2, wave-per-row ----------------
__global__ __launch_bounds__(256) void psi_kernel(
    const short* __restrict__ S1, const float* __restrict__ W2,
    const float* __restrict__ b2, float* __restrict__ psi)
{
  const int lane = threadIdx.x & 63;
  const int wv = threadIdx.x >> 6;
  const int m = blockIdx.x * 4 + wv;
  float a0 = 0.f, a1 = 0.f, a2 = 0.f, a3 = 0.f;
#pragma unroll
  for (int t = 0; t < 6; ++t) {
    int k = lane + t * 64;
    float sv = bf2f(S1[m * 384 + k]);
    float4 wr = *(const float4*)(W2 + k * 4);
    a0 += sv * wr.x; a1 += sv * wr.y; a2 += sv * wr.z; a3 += sv * wr.w;
  }
  for (int off = 32; off > 0; off >>= 1) {
    a0 += __shfl_down(a0, off, 64);
    a1 += __shfl_down(a1, off, 64);
    a2 += __shfl_down(a2, off, 64);
    a3 += __shfl_down(a3, off, 64);
  }
  if (lane == 0) {
    int bb = m >> 12, n = m & 4095;
    psi[(bb * 4 + 0) * 4096 + n] = a0 + b2[0];
    psi[(bb * 4 + 1) * 4096 + n] = a1 + b2[1];
    psi[(bb * 4 + 2) * 4096 + n] = a2 + b2[2];
    psi[(bb * 4 + 3) * 4096 + n] = a3 + b2[3];
  }
}

// ---------------- routing: central diffs + softmax(5) ----------------
__global__ __launch_bounds__(256) void routing_kernel(
    const float* __restrict__ psi, const float* __restrict__ sb,
    float* __restrict__ R)
{
  const int idx = blockIdx.x * 256 + threadIdx.x;   // < 131072
  const int n = idx & 4095, bg = idx >> 12;
  const int i = n >> 6, j = n & 63;
  const float* p = psi + bg * 4096;
  float up = (i > 0)  ? p[n - 64] : 0.f;
  float dn = (i < 63) ? p[n + 64] : 0.f;
  float lf = (j > 0)  ? p[n - 1]  : 0.f;
  float rt = (j < 63) ? p[n + 1]  : 0.f;
  float vx = 0.5f * (dn - up);
  float vy = -0.5f * (rt - lf);
  float l0 = sb[bg & 3];
  float l1 = -vx * TAU_INV, l2 = vx * TAU_INV, l3 = -vy * TAU_INV, l4v = vy * TAU_INV;
  float mx = fmaxf(fmaxf(fmaxf(l0, l1), fmaxf(l2, l3)), l4v);
  float e0 = __expf(l0 - mx), e1 = __expf(l1 - mx), e2 = __expf(l2 - mx);
  float e3 = __expf(l3 - mx), e4 = __expf(l4v - mx);
  float inv = 1.f / (e0 + e1 + e2 + e3 + e4);
  const int NP = 8 * 4 * 4096;
  R[0 * NP + idx] = e0 * inv;
  R[1 * NP + idx] = e1 * inv;
  R[2 * NP + idx] = e2 * inv;
  R[3 * NP + idx] = e3 * inv;
  R[4 * NP + idx] = e4 * inv;
}

// ---------------- transport: 4 gated stencil steps, double-buffered float2 LDS ----------------
__global__ __launch_bounds__(512, 4) void transport_kernel(
    short* __restrict__ Ug, short* __restrict__ Vg,
    const short* __restrict__ Ga, const short* __restrict__ Gb,
    const short* __restrict__ Xu, const short* __restrict__ Xv,
    const float* __restrict__ R, const int* __restrict__ ksp)
{
  __shared__ float2 sb[2][4096];
  const int tid = threadIdx.x;
  const int bd = blockIdx.x;            // b*384 + d
  const int b = bd / 384;
  const int d = bd - b * 384;
  const int g = d / 96;
  const int pbase = bd * 4096;
  const int rbase = (b * 4 + g) * 4096;
  const int NP = 8 * 4 * 4096;
  const int p0 = tid * 8;
  const int i = tid >> 3;
  const int j0 = (tid & 7) * 8;
  const int s = i & 7;                  // per-row XOR swizzle of the 8-elem group

  // gates/injection pre-scaled: ar_k = ga*r_k ; bxu = gb*xu ; bxv = gb*xv
  float ar0[8], ar1[8], ar2[8], ar3[8], ar4[8], bxu[8], bxv[8];
  float cu[8], cv[8];
  {
    float ga[8], gb[8];
    bf16x8 t;
    t = *(const bf16x8*)(Ga + pbase + p0);
#pragma unroll
    for (int c = 0; c < 8; ++c) ga[c] = bf2f(t[c]);
    t = *(const bf16x8*)(Gb + pbase + p0);
#pragma unroll
    for (int c = 0; c < 8; ++c) gb[c] = bf2f(t[c]);
    t = *(const bf16x8*)(Xu + pbase + p0);
#pragma unroll
    for (int c = 0; c < 8; ++c) bxu[c] = gb[c] * bf2f(t[c]);
    t = *(const bf16x8*)(Xv + pbase + p0);
#pragma unroll
    for (int c = 0; c < 8; ++c) bxv[c] = gb[c] * bf2f(t[c]);
#pragma unroll
    for (int q = 0; q < 2; ++q) {
      float4 f0 = *(const float4*)(R + 0 * NP + rbase + p0 + q * 4);
      float4 f1 = *(const float4*)(R + 1 * NP + rbase + p0 + q * 4);
      float4 f2 = *(const float4*)(R + 2 * NP + rbase + p0 + q * 4);
      float4 f3 = *(const float4*)(R + 3 * NP + rbase + p0 + q * 4);
      float4 f4 = *(const float4*)(R + 4 * NP + rbase + p0 + q * 4);
      ar0[q*4+0]=ga[q*4+0]*f0.x; ar0[q*4+1]=ga[q*4+1]*f0.y; ar0[q*4+2]=ga[q*4+2]*f0.z; ar0[q*4+3]=ga[q*4+3]*f0.w;
      ar1[q*4+0]=ga[q*4+0]*f1.x; ar1[q*4+1]=ga[q*4+1]*f1.y; ar1[q*4+2]=ga[q*4+2]*f1.z; ar1[q*4+3]=ga[q*4+3]*f1.w;
      ar2[q*4+0]=ga[q*4+0]*f2.x; ar2[q*4+1]=ga[q*4+1]*f2.y; ar2[q*4+2]=ga[q*4+2]*f2.z; ar2[q*4+3]=ga[q*4+3]*f2.w;
      ar3[q*4+0]=ga[q*4+0]*f3.x; ar3[q*4+1]=ga[q*4+1]*f3.y; ar3[q*4+2]=ga[q*4+2]*f3.z; ar3[q*4+3]=ga[q*4+3]*f3.w;
      ar4[q*4+0]=ga[q*4+0]*f4.x; ar4[q*4+1]=ga[q*4+1]*f4.y; ar4[q*4+2]=ga[q*4+2]*f4.z; ar4[q*4+3]=ga[q*4+3]*f4.w;
    }
    bf16x8 tu = *(const bf16x8*)(Ug + pbase + p0);
    bf16x8 tv = *(const bf16x8*)(Vg + pbase + p0);
#pragma unroll
    for (int c = 0; c < 8; ++c) {
      cu[c] = bf2f(tu[c]); cv[c] = bf2f(tv[c]);
      sb[0][p0 + (c ^ s)] = make_float2(cu[c], cv[c]);
    }
  }
  __syncthreads();
  const int ks = ksp[0];
  const bool hasUp = (i > 0), hasDn = (i < 63);
  const int sU = (i - 1) & 7, sD = (i + 1) & 7;
  int cur = 0;
  for (int step = 0; step < ks; ++step) {
    const float2* __restrict__ buf = sb[cur];
    float2* __restrict__ nxt = sb[cur ^ 1];
    float2 lfe = (j0 > 0)  ? buf[(p0 - 1) ^ s] : make_float2(0.f, 0.f);
    float2 rte = (j0 < 56) ? buf[(p0 + 8) ^ s] : make_float2(0.f, 0.f);
    float nu[8], nv[8];
#pragma unroll
    for (int c = 0; c < 8; ++c) {
      float2 up = hasUp ? buf[(p0 - 64) + (c ^ sU)] : make_float2(0.f, 0.f);
      float2 dn = hasDn ? buf[(p0 + 64) + (c ^ sD)] : make_float2(0.f, 0.f);
      float lfU = (c > 0) ? cu[c - 1] : lfe.x;
      float lfV = (c > 0) ? cv[c - 1] : lfe.y;
      float rtU = (c < 7) ? cu[c + 1] : rte.x;
      float rtV = (c < 7) ? cv[c + 1] : rte.y;
      nu[c] = ar0[c]*cu[c] + ar1[c]*up.x + ar2[c]*dn.x + ar3[c]*lfU + ar4[c]*rtU + bxu[c];
      nv[c] = ar0[c]*cv[c] + ar1[c]*up.y + ar2[c]*dn.y + ar3[c]*lfV + ar4[c]*rtV + bxv[c];
    }
#pragma unroll
    for (int c = 0; c < 8; ++c) {
      nxt[p0 + (c ^ s)] = make_float2(nu[c], nv[c]);
      cu[c] = nu[c]; cv[c] = nv[c];
    }
    __syncthreads();
    cur ^= 1;
  }
  bf16x8 ou, ov;
#pragma unroll
  for (int c = 0; c < 8; ++c) { ou[c] = f2bf(cu[c]); ov[c] = f2bf(cv[c]); }
  *(bf16x8*)(Ug + pbase + p0) = ou;
  *(bf16x8*)(Vg + pbase + p0) = ov;
}

// ---------------- final GEMM: [u|v] @ W_out + x*D_skip ----------------
__global__ __launch_bounds__(256) void gemm_final(
    const short* __restrict__ U, const short* __restrict__ V,
    const short* __restrict__ Wt, const float* __restrict__ X,
    const float* __restrict__ Dskip, float* __restrict__ out)
{
  __shared__ short As[64 * 128];   // [k][m], 16B-chunk swizzled
  __shared__ short Bs[128 * 72];   // [c][k]
  const int tid = threadIdx.x;
  const int lane = tid & 63;
  const int wv = tid >> 6, wr = wv >> 1, wc = wv & 1;
  const int m0 = blockIdx.x * 128, c0 = blockIdx.y * 128;
  const int b = m0 >> 12, n0 = m0 & 4095;
  const int l15 = lane & 15, l4 = lane >> 4;
  f32x4 acc[4][4] = {};
  for (int k0 = 0; k0 < 768; k0 += 64) {
    const short* src = (k0 < 384) ? U : V;
    const int kp = (k0 >= 384) ? (k0 - 384) : k0;
    __syncthreads();
#pragma unroll
    for (int i = 0; i < 4; ++i) {
      int h = tid + i * 256;
      int k = h >> 4, cc = h & 15;
      bf16x8 tv = *(const bf16x8*)(src + (b * 384 + kp + k) * 4096 + n0 + cc * 8);
      int ccs = cc ^ (((k >> 3) & 3) << 1);
      *(bf16x8*)(As + k * 128 + ccs * 8) = tv;
    }
#pragma unroll
    for (int i = 0; i < 4; ++i) {
      int h = tid + i * 256;
      int c = h >> 3, kc = (h & 7) * 8;
      bf16x8 wvv = *(const bf16x8*)(Wt + (c0 + c) * 768 + k0 + kc);
      *(bf16x8*)(Bs + c * 72 + kc) = wvv;
    }
    __syncthreads();
#pragma unroll
    for (int kk = 0; kk < 2; ++kk) {
      bf16x8 af[4], bfv[4];
#pragma unroll
      for (int f = 0; f < 4; ++f) {
        const int mm = wr * 64 + f * 16 + l15;
        const int chunk = mm >> 3, wi = mm & 7;
        bf16x8 av;
#pragma unroll
        for (int jj = 0; jj < 8; ++jj) {
          int k = kk * 32 + l4 * 8 + jj;
          int ccs = chunk ^ (((k >> 3) & 3) << 1);
          av[jj] = As[k * 128 + ccs * 8 + wi];
        }
        af[f] = av;
        bfv[f] = *(const bf16x8*)(Bs + (wc * 64 + f * 16 + l15) * 72 + kk * 32 + l4 * 8);
      }
#pragma unroll
      for (int i = 0; i < 4; ++i)
#pragma unroll
        for (int j = 0; j < 4; ++j)
          acc[i][j] = __builtin_amdgcn_mfma_f32_16x16x32_bf16(af[i], bfv[j], acc[i][j], 0, 0, 0);
    }
  }
#pragma unroll
  for (int i = 0; i < 4; ++i)
#pragma unroll
    for (int j = 0; j < 4; ++j) {
      const int c = c0 + wc * 64 + j * 16 + l15;
      const int mb = m0 + wr * 64 + i * 16 + l4 * 4;
      const float ds = Dskip[c];
#pragma unroll
      for (int r = 0; r < 4; ++r) {
        int idx = (mb + r) * 384 + c;
        out[idx] = acc[i][j][r] + X[idx] * ds;
      }
    }
}

extern "C" void kernel_launch(void* const* d_in, const int* in_sizes, int n_in,
                              void* d_out, int out_size, void* d_ws, size_t ws_size,
                              hipStream_t stream) {
  (void)in_sizes; (void)n_in; (void)out_size; (void)ws_size;
  const float* x       = (const float*)d_in[0];
  const float* w_s1    = (const float*)d_in[1];
  const float* b_s1    = (const float*)d_in[2];
  const float* w_s2    = (const float*)d_in[3];
  const float* b_s2    = (const float*)d_in[4];
  const float* sb      = (const float*)d_in[5];
  const float* w_ga    = (const float*)d_in[6];
  const float* b_ga    = (const float*)d_in[7];
  const float* w_gb    = (const float*)d_in[8];
  const float* b_gb    = (const float*)d_in[9];
  const float* w_inj   = (const float*)d_in[10];
  const float* w_state = (const float*)d_in[11];
  const float* w_out   = (const float*)d_in[12];
  const float* dskip   = (const float*)d_in[13];
  const int*   ksp     = (const int*)d_in[14];
  float* out = (float*)d_out;

  char* ws = (char*)d_ws;
  size_t off = 0;
  auto alloc = [&](size_t bytes) -> void* {
    void* p = ws + off;
    off += (bytes + 255) & ~(size_t)255;
    return p;
  };
  short* t_cat = (short*)alloc((size_t)2688 * 384 * 2);
  short* t_out = (short*)alloc((size_t)384 * 768 * 2);
  const size_t PL = (size_t)8 * 384 * 4096;
  short* xb  = (short*)alloc(PL * 2);
  short* ug  = (short*)alloc(PL * 2);
  short* vg  = (short*)alloc(PL * 2);
  short* xug = (short*)alloc(PL * 2);
  short* xvg = (short*)alloc(PL * 2);
  short* gag = (short*)alloc(PL * 2);
  short* gbg = (short*)alloc(PL * 2);
  short* s1  = (short*)alloc(PL * 2);
  float* psi = (float*)alloc((size_t)8 * 4 * 4096 * 4);
  float* R   = (float*)alloc((size_t)5 * 8 * 4 * 4096 * 4);

  prep_weights<<<dim3(5184), dim3(256), 0, stream>>>(
      w_state, w_inj, w_ga, w_gb, w_s1, w_out, t_cat, t_out);
  prep_x<<<dim3(6144), dim3(256), 0, stream>>>(x, xb);
  gemm_fused<<<dim3(256, 21), dim3(256), 0, stream>>>(
      xb, t_cat, b_ga, b_gb, b_s1, ug, vg, xug, xvg, gag, gbg, s1);
  psi_kernel<<<dim3(8192), dim3(256), 0, stream>>>(s1, w_s2, b_s2, psi);
  routing_kernel<<<dim3(512), dim3(256), 0, stream>>>(psi, sb, R);
  transport_kernel<<<dim3(3072), dim3(512), 0, stream>>>(ug, vg, gag, gbg, xug, xvg, R, ksp);
  gemm_final<<<dim3(256, 3), dim3(256), 0, stream>>>(ug, vg, t_out, x, dskip, out);
}

// Round 4
// 690.848 us; speedup vs baseline: 1.0273x; 1.0273x over previous
//
#include <hip/hip_runtime.h>
#include <hip/hip_bf16.h>

typedef __attribute__((ext_vector_type(8))) short bf16x8;
typedef __attribute__((ext_vector_type(4))) short short4v;
typedef __attribute__((ext_vector_type(4))) float f32x4;

#define TAU_INV 2.0f

__device__ __forceinline__ short f2bf(float f) {
  unsigned u = __float_as_uint(f);
  u += 0x7fffu + ((u >> 16) & 1u);
  return (short)(u >> 16);
}
__device__ __forceinline__ float bf2f(short s) {
  return __uint_as_float(((unsigned)(unsigned short)s) << 16);
}

// ---------------- weight prep: concat-transpose to [c][k] bf16 ----------------
__global__ __launch_bounds__(256) void prep_weights(
    const float* __restrict__ w_state, const float* __restrict__ w_inj,
    const float* __restrict__ w_ga, const float* __restrict__ w_gb,
    const float* __restrict__ w_s1, const float* __restrict__ w_out,
    short* __restrict__ t_cat, short* __restrict__ t_out)
{
  int idx = blockIdx.x * 256 + threadIdx.x;
  const int NCAT = 2688 * 384;
  if (idx < NCAT) {
    int c = idx / 384, k = idx - c * 384;
    float v;
    if (c < 768)        v = w_state[k * 768 + c];
    else if (c < 1536)  v = w_inj[k * 768 + (c - 768)];
    else if (c < 1920)  v = w_ga[k * 384 + (c - 1536)];
    else if (c < 2304)  v = w_gb[k * 384 + (c - 1920)];
    else                v = w_s1[k * 384 + (c - 2304)];
    t_cat[idx] = f2bf(v);
  } else {
    int j = idx - NCAT;           // < 384*768
    int c = j / 768, k = j - c * 768;
    t_out[c * 768 + k] = f2bf(w_out[k * 384 + c]);
  }
}

// ---------------- x -> bf16 once ----------------
__global__ __launch_bounds__(256) void prep_x(
    const float* __restrict__ X, short* __restrict__ Xb)
{
  int t = blockIdx.x * 256 + threadIdx.x;
  int base = t * 8;
  float4 a = *(const float4*)(X + base);
  float4 b = *(const float4*)(X + base + 4);
  bf16x8 s;
  s[0] = f2bf(a.x); s[1] = f2bf(a.y); s[2] = f2bf(a.z); s[3] = f2bf(a.w);
  s[4] = f2bf(b.x); s[5] = f2bf(b.y); s[6] = f2bf(b.z); s[7] = f2bf(b.w);
  *(bf16x8*)(Xb + base) = s;
}

// ---------------- fused GEMM over x: all 5 projections in one pass ----------------
__global__ __launch_bounds__(256) void gemm_fused(
    const short* __restrict__ Xb, const short* __restrict__ Wt,
    const float* __restrict__ b_ga, const float* __restrict__ b_gb,
    const float* __restrict__ b_s1,
    short* __restrict__ ug, short* __restrict__ vg,
    short* __restrict__ xug, short* __restrict__ xvg,
    short* __restrict__ gag, short* __restrict__ gbg,
    short* __restrict__ s1)
{
  __shared__ short As[128 * 72];
  __shared__ short Bs[128 * 72];
  const int tid = threadIdx.x;
  const int lane = tid & 63;
  const int wv = tid >> 6;
  const int wr = wv >> 1, wc = wv & 1;
  const int m0 = blockIdx.x * 128, c0 = blockIdx.y * 128;
  const int l15 = lane & 15, l4 = lane >> 4;
  f32x4 acc[4][4] = {};
  for (int k0 = 0; k0 < 384; k0 += 64) {
    __syncthreads();
#pragma unroll
    for (int i = 0; i < 4; ++i) {
      int h = tid + i * 256;
      int m = h >> 3, kc = (h & 7) * 8;
      bf16x8 xv = *(const bf16x8*)(Xb + (m0 + m) * 384 + k0 + kc);
      *(bf16x8*)(As + m * 72 + kc) = xv;
    }
#pragma unroll
    for (int i = 0; i < 4; ++i) {
      int h = tid + i * 256;
      int c = h >> 3, kc = (h & 7) * 8;
      bf16x8 wvv = *(const bf16x8*)(Wt + (c0 + c) * 384 + k0 + kc);
      *(bf16x8*)(Bs + c * 72 + kc) = wvv;
    }
    __syncthreads();
#pragma unroll
    for (int kk = 0; kk < 2; ++kk) {
      bf16x8 af[4], bfv[4];
#pragma unroll
      for (int f = 0; f < 4; ++f) {
        af[f]  = *(const bf16x8*)(As + (wr * 64 + f * 16 + l15) * 72 + kk * 32 + l4 * 8);
        bfv[f] = *(const bf16x8*)(Bs + (wc * 64 + f * 16 + l15) * 72 + kk * 32 + l4 * 8);
      }
#pragma unroll
      for (int i = 0; i < 4; ++i)
#pragma unroll
        for (int j = 0; j < 4; ++j)
          acc[i][j] = __builtin_amdgcn_mfma_f32_16x16x32_bf16(af[i], bfv[j], acc[i][j], 0, 0, 0);
    }
  }
#pragma unroll
  for (int i = 0; i < 4; ++i) {
#pragma unroll
    for (int j = 0; j < 4; ++j) {
      const int c = c0 + wc * 64 + j * 16 + l15;
      const int mb = m0 + wr * 64 + i * 16 + l4 * 4;
      const int b = mb >> 12, n = mb & 4095;
      f32x4 v = acc[i][j];
      if (c < 1536) {               // state / inj -> grid split stores
        int cc = (c >= 768) ? (c - 768) : c;
        short* base;
        if (c < 768) base = (cc < 384) ? ug : vg;
        else         base = (cc < 384) ? xug : xvg;
        int plane = (cc >= 384) ? (cc - 384) : cc;
        short4v s;
        s[0] = f2bf(v[0]); s[1] = f2bf(v[1]); s[2] = f2bf(v[2]); s[3] = f2bf(v[3]);
        *(short4v*)(base + (b * 384 + plane) * 4096 + n) = s;
      } else if (c < 2304) {        // gates: sigmoid
        const float* bias = (c < 1920) ? b_ga : b_gb;
        short* base = (c < 1920) ? gag : gbg;
        int plane = (c < 1920) ? (c - 1536) : (c - 1920);
        float bb = bias[plane];
        short4v s;
#pragma unroll
        for (int r = 0; r < 4; ++r) {
          float t = v[r] + bb;
          s[r] = f2bf(1.f / (1.f + __expf(-t)));
        }
        *(short4v*)(base + (b * 384 + plane) * 4096 + n) = s;
      } else {                      // s1: silu, natural [m][c] layout
        int plane = c - 2304;
        float bb = b_s1[plane];
#pragma unroll
        for (int r = 0; r < 4; ++r) {
          float t = v[r] + bb;
          float sg = 1.f / (1.f + __expf(-t));
          s1[(mb + r) * 384 + plane] = f2bf(t * sg);
        }
      }
    }
  }
}

// ---------------- psi: s1 @ W_stream2 + b2, wave-per-row ----------------
__global__ __launch_bounds__(256) void psi_kernel(
    const short* __restrict__ S1, const float* __restrict__ W2,
    const float* __restrict__ b2, float* __restrict__ psi)
{
  const int lane = threadIdx.x & 63;
  const int wv = threadIdx.x >> 6;
  const int m = blockIdx.x * 4 + wv;
  float a0 = 0.f, a1 = 0.f, a2 = 0.f, a3 = 0.f;
#pragma unroll
  for (int t = 0; t < 6; ++t) {
    int k = lane + t * 64;
    float sv = bf2f(S1[m * 384 + k]);
    float4 wr = *(const float4*)(W2 + k * 4);
    a0 += sv * wr.x; a1 += sv * wr.y; a2 += sv * wr.z; a3 += sv * wr.w;
  }
  for (int off = 32; off > 0; off >>= 1) {
    a0 += __shfl_down(a0, off, 64);
    a1 += __shfl_down(a1, off, 64);
    a2 += __shfl_down(a2, off, 64);
    a3 += __shfl_down(a3, off, 64);
  }
  if (lane == 0) {
    int bb = m >> 12, n = m & 4095;
    psi[(bb * 4 + 0) * 4096 + n] = a0 + b2[0];
    psi[(bb * 4 + 1) * 4096 + n] = a1 + b2[1];
    psi[(bb * 4 + 2) * 4096 + n] = a2 + b2[2];
    psi[(bb * 4 + 3) * 4096 + n] = a3 + b2[3];
  }
}

// ---------------- routing: central diffs + softmax(5) ----------------
__global__ __launch_bounds__(256) void routing_kernel(
    const float* __restrict__ psi, const float* __restrict__ sb,
    float* __restrict__ R)
{
  const int idx = blockIdx.x * 256 + threadIdx.x;   // < 131072
  const int n = idx & 4095, bg = idx >> 12;
  const int i = n >> 6, j = n & 63;
  const float* p = psi + bg * 4096;
  float up = (i > 0)  ? p[n - 64] : 0.f;
  float dn = (i < 63) ? p[n + 64] : 0.f;
  float lf = (j > 0)  ? p[n - 1]  : 0.f;
  float rt = (j < 63) ? p[n + 1]  : 0.f;
  float vx = 0.5f * (dn - up);
  float vy = -0.5f * (rt - lf);
  float l0 = sb[bg & 3];
  float l1 = -vx * TAU_INV, l2 = vx * TAU_INV, l3 = -vy * TAU_INV, l4v = vy * TAU_INV;
  float mx = fmaxf(fmaxf(fmaxf(l0, l1), fmaxf(l2, l3)), l4v);
  float e0 = __expf(l0 - mx), e1 = __expf(l1 - mx), e2 = __expf(l2 - mx);
  float e3 = __expf(l3 - mx), e4 = __expf(l4v - mx);
  float inv = 1.f / (e0 + e1 + e2 + e3 + e4);
  const int NP = 8 * 4 * 4096;
  R[0 * NP + idx] = e0 * inv;
  R[1 * NP + idx] = e1 * inv;
  R[2 * NP + idx] = e2 * inv;
  R[3 * NP + idx] = e3 * inv;
  R[4 * NP + idx] = e4 * inv;
}

// ---------------- transport: 4 gated stencil steps, float2 LDS, spill-safe ----------------
// __launch_bounds__(512,4): 4 waves/EU -> VGPR cap 128, 2 blocks/CU (32KB LDS).
// No register state carried across the step loop except ar*/bx* (56 floats);
// center/result re-read from LDS each step to stay under the cap (r3 spilled).
__global__ __launch_bounds__(512, 4) void transport_kernel(
    short* __restrict__ Ug, short* __restrict__ Vg,
    const short* __restrict__ Ga, const short* __restrict__ Gb,
    const short* __restrict__ Xu, const short* __restrict__ Xv,
    const float* __restrict__ R, const int* __restrict__ ksp)
{
  __shared__ float2 smem[4096];
  const int tid = threadIdx.x;
  const int bd = blockIdx.x;            // b*384 + d
  const int b = bd / 384;
  const int d = bd - b * 384;
  const int g = d / 96;
  const int pbase = bd * 4096;
  const int rbase = (b * 4 + g) * 4096;
  const int NP = 8 * 4 * 4096;
  const int p0 = tid * 8;
  const int i = tid >> 3;
  const int j0 = (tid & 7) * 8;
  const int s = i & 7;                  // per-row XOR swizzle within 8-elem group

  float ar0[8], ar1[8], ar2[8], ar3[8], ar4[8], bxu[8], bxv[8];
  {
    float ga[8], gb[8];
    bf16x8 t;
    t = *(const bf16x8*)(Ga + pbase + p0);
#pragma unroll
    for (int c = 0; c < 8; ++c) ga[c] = bf2f(t[c]);
    t = *(const bf16x8*)(Gb + pbase + p0);
#pragma unroll
    for (int c = 0; c < 8; ++c) gb[c] = bf2f(t[c]);
    t = *(const bf16x8*)(Xu + pbase + p0);
#pragma unroll
    for (int c = 0; c < 8; ++c) bxu[c] = gb[c] * bf2f(t[c]);
    t = *(const bf16x8*)(Xv + pbase + p0);
#pragma unroll
    for (int c = 0; c < 8; ++c) bxv[c] = gb[c] * bf2f(t[c]);
#pragma unroll
    for (int q = 0; q < 2; ++q) {
      float4 f0 = *(const float4*)(R + 0 * NP + rbase + p0 + q * 4);
      float4 f1 = *(const float4*)(R + 1 * NP + rbase + p0 + q * 4);
      float4 f2 = *(const float4*)(R + 2 * NP + rbase + p0 + q * 4);
      float4 f3 = *(const float4*)(R + 3 * NP + rbase + p0 + q * 4);
      float4 f4 = *(const float4*)(R + 4 * NP + rbase + p0 + q * 4);
      ar0[q*4+0]=ga[q*4+0]*f0.x; ar0[q*4+1]=ga[q*4+1]*f0.y; ar0[q*4+2]=ga[q*4+2]*f0.z; ar0[q*4+3]=ga[q*4+3]*f0.w;
      ar1[q*4+0]=ga[q*4+0]*f1.x; ar1[q*4+1]=ga[q*4+1]*f1.y; ar1[q*4+2]=ga[q*4+2]*f1.z; ar1[q*4+3]=ga[q*4+3]*f1.w;
      ar2[q*4+0]=ga[q*4+0]*f2.x; ar2[q*4+1]=ga[q*4+1]*f2.y; ar2[q*4+2]=ga[q*4+2]*f2.z; ar2[q*4+3]=ga[q*4+3]*f2.w;
      ar3[q*4+0]=ga[q*4+0]*f3.x; ar3[q*4+1]=ga[q*4+1]*f3.y; ar3[q*4+2]=ga[q*4+2]*f3.z; ar3[q*4+3]=ga[q*4+3]*f3.w;
      ar4[q*4+0]=ga[q*4+0]*f4.x; ar4[q*4+1]=ga[q*4+1]*f4.y; ar4[q*4+2]=ga[q*4+2]*f4.z; ar4[q*4+3]=ga[q*4+3]*f4.w;
    }
    bf16x8 tu = *(const bf16x8*)(Ug + pbase + p0);
    bf16x8 tv = *(const bf16x8*)(Vg + pbase + p0);
#pragma unroll
    for (int c = 0; c < 8; ++c)
      smem[p0 + (c ^ s)] = make_float2(bf2f(tu[c]), bf2f(tv[c]));
  }
  __syncthreads();
  const int ks = ksp[0];
  const bool hasUp = (i > 0), hasDn = (i < 63);
  const int sU = (i - 1) & 7, sD = (i + 1) & 7;
  for (int step = 0; step < ks; ++step) {
    float cu[8], cv[8], nu[8], nv[8];
#pragma unroll
    for (int c = 0; c < 8; ++c) {
      float2 ce = smem[p0 + (c ^ s)];
      cu[c] = ce.x; cv[c] = ce.y;
    }
    float2 lfe = (j0 > 0)  ? smem[(p0 - 1) ^ s] : make_float2(0.f, 0.f);
    float2 rte = (j0 < 56) ? smem[(p0 + 8) ^ s] : make_float2(0.f, 0.f);
#pragma unroll
    for (int c = 0; c < 8; ++c) {
      float2 up = hasUp ? smem[(p0 - 64) + (c ^ sU)] : make_float2(0.f, 0.f);
      float2 dn = hasDn ? smem[(p0 + 64) + (c ^ sD)] : make_float2(0.f, 0.f);
      float lfU = (c > 0) ? cu[c - 1] : lfe.x;
      float lfV = (c > 0) ? cv[c - 1] : lfe.y;
      float rtU = (c < 7) ? cu[c + 1] : rte.x;
      float rtV = (c < 7) ? cv[c + 1] : rte.y;
      nu[c] = ar0[c]*cu[c] + ar1[c]*up.x + ar2[c]*dn.x + ar3[c]*lfU + ar4[c]*rtU + bxu[c];
      nv[c] = ar0[c]*cv[c] + ar1[c]*up.y + ar2[c]*dn.y + ar3[c]*lfV + ar4[c]*rtV + bxv[c];
    }
    __syncthreads();
#pragma unroll
    for (int c = 0; c < 8; ++c)
      smem[p0 + (c ^ s)] = make_float2(nu[c], nv[c]);
    __syncthreads();
  }
  bf16x8 ou, ov;
#pragma unroll
  for (int c = 0; c < 8; ++c) {
    float2 t = smem[p0 + (c ^ s)];
    ou[c] = f2bf(t.x); ov[c] = f2bf(t.y);
  }
  *(bf16x8*)(Ug + pbase + p0) = ou;
  *(bf16x8*)(Vg + pbase + p0) = ov;
}

// ---------------- final GEMM: [u|v] @ W_out + x*D_skip ----------------
__global__ __launch_bounds__(256) void gemm_final(
    const short* __restrict__ U, const short* __restrict__ V,
    const short* __restrict__ Wt, const float* __restrict__ X,
    const float* __restrict__ Dskip, float* __restrict__ out)
{
  __shared__ short As[64 * 128];   // [k][m], 16B-chunk swizzled
  __shared__ short Bs[128 * 72];   // [c][k]
  const int tid = threadIdx.x;
  const int lane = tid & 63;
  const int wv = tid >> 6, wr = wv >> 1, wc = wv & 1;
  const int m0 = blockIdx.x * 128, c0 = blockIdx.y * 128;
  const int b = m0 >> 12, n0 = m0 & 4095;
  const int l15 = lane & 15, l4 = lane >> 4;
  f32x4 acc[4][4] = {};
  for (int k0 = 0; k0 < 768; k0 += 64) {
    const short* src = (k0 < 384) ? U : V;
    const int kp = (k0 >= 384) ? (k0 - 384) : k0;
    __syncthreads();
#pragma unroll
    for (int i = 0; i < 4; ++i) {
      int h = tid + i * 256;
      int k = h >> 4, cc = h & 15;
      bf16x8 tv = *(const bf16x8*)(src + (b * 384 + kp + k) * 4096 + n0 + cc * 8);
      int ccs = cc ^ (((k >> 3) & 3) << 1);
      *(bf16x8*)(As + k * 128 + ccs * 8) = tv;
    }
#pragma unroll
    for (int i = 0; i < 4; ++i) {
      int h = tid + i * 256;
      int c = h >> 3, kc = (h & 7) * 8;
      bf16x8 wvv = *(const bf16x8*)(Wt + (c0 + c) * 768 + k0 + kc);
      *(bf16x8*)(Bs + c * 72 + kc) = wvv;
    }
    __syncthreads();
#pragma unroll
    for (int kk = 0; kk < 2; ++kk) {
      bf16x8 af[4], bfv[4];
#pragma unroll
      for (int f = 0; f < 4; ++f) {
        const int mm = wr * 64 + f * 16 + l15;
        const int chunk = mm >> 3, wi = mm & 7;
        bf16x8 av;
#pragma unroll
        for (int jj = 0; jj < 8; ++jj) {
          int k = kk * 32 + l4 * 8 + jj;
          int ccs = chunk ^ (((k >> 3) & 3) << 1);
          av[jj] = As[k * 128 + ccs * 8 + wi];
        }
        af[f] = av;
        bfv[f] = *(const bf16x8*)(Bs + (wc * 64 + f * 16 + l15) * 72 + kk * 32 + l4 * 8);
      }
#pragma unroll
      for (int i = 0; i < 4; ++i)
#pragma unroll
        for (int j = 0; j < 4; ++j)
          acc[i][j] = __builtin_amdgcn_mfma_f32_16x16x32_bf16(af[i], bfv[j], acc[i][j], 0, 0, 0);
    }
  }
#pragma unroll
  for (int i = 0; i < 4; ++i)
#pragma unroll
    for (int j = 0; j < 4; ++j) {
      const int c = c0 + wc * 64 + j * 16 + l15;
      const int mb = m0 + wr * 64 + i * 16 + l4 * 4;
      const float ds = Dskip[c];
#pragma unroll
      for (int r = 0; r < 4; ++r) {
        int idx = (mb + r) * 384 + c;
        out[idx] = acc[i][j][r] + X[idx] * ds;
      }
    }
}

extern "C" void kernel_launch(void* const* d_in, const int* in_sizes, int n_in,
                              void* d_out, int out_size, void* d_ws, size_t ws_size,
                              hipStream_t stream) {
  (void)in_sizes; (void)n_in; (void)out_size; (void)ws_size;
  const float* x       = (const float*)d_in[0];
  const float* w_s1    = (const float*)d_in[1];
  const float* b_s1    = (const float*)d_in[2];
  const float* w_s2    = (const float*)d_in[3];
  const float* b_s2    = (const float*)d_in[4];
  const float* sb      = (const float*)d_in[5];
  const float* w_ga    = (const float*)d_in[6];
  const float* b_ga    = (const float*)d_in[7];
  const float* w_gb    = (const float*)d_in[8];
  const float* b_gb    = (const float*)d_in[9];
  const float* w_inj   = (const float*)d_in[10];
  const float* w_state = (const float*)d_in[11];
  const float* w_out   = (const float*)d_in[12];
  const float* dskip   = (const float*)d_in[13];
  const int*   ksp     = (const int*)d_in[14];
  float* out = (float*)d_out;

  char* ws = (char*)d_ws;
  size_t off = 0;
  auto alloc = [&](size_t bytes) -> void* {
    void* p = ws + off;
    off += (bytes + 255) & ~(size_t)255;
    return p;
  };
  short* t_cat = (short*)alloc((size_t)2688 * 384 * 2);
  short* t_out = (short*)alloc((size_t)384 * 768 * 2);
  const size_t PL = (size_t)8 * 384 * 4096;
  short* xb  = (short*)alloc(PL * 2);
  short* ug  = (short*)alloc(PL * 2);
  short* vg  = (short*)alloc(PL * 2);
  short* xug = (short*)alloc(PL * 2);
  short* xvg = (short*)alloc(PL * 2);
  short* gag = (short*)alloc(PL * 2);
  short* gbg = (short*)alloc(PL * 2);
  short* s1  = (short*)alloc(PL * 2);
  float* psi = (float*)alloc((size_t)8 * 4 * 4096 * 4);
  float* R   = (float*)alloc((size_t)5 * 8 * 4 * 4096 * 4);

  prep_weights<<<dim3(5184), dim3(256), 0, stream>>>(
      w_state, w_inj, w_ga, w_gb, w_s1, w_out, t_cat, t_out);
  prep_x<<<dim3(6144), dim3(256), 0, stream>>>(x, xb);
  gemm_fused<<<dim3(256, 21), dim3(256), 0, stream>>>(
      xb, t_cat, b_ga, b_gb, b_s1, ug, vg, xug, xvg, gag, gbg, s1);
  psi_kernel<<<dim3(8192), dim3(256), 0, stream>>>(s1, w_s2, b_s2, psi);
  routing_kernel<<<dim3(512), dim3(256), 0, stream>>>(psi, sb, R);
  transport_kernel<<<dim3(3072), dim3(512), 0, stream>>>(ug, vg, gag, gbg, xug, xvg, R, ksp);
  gemm_final<<<dim3(256, 3), dim3(256), 0, stream>>>(ug, vg, t_out, x, dskip, out);
}

// Round 5
// 412.588 us; speedup vs baseline: 1.7201x; 1.6744x over previous
//
#include <hip/hip_runtime.h>
#include <hip/hip_bf16.h>

typedef __attribute__((ext_vector_type(8))) short bf16x8;
typedef __attribute__((ext_vector_type(4))) short short4v;
typedef __attribute__((ext_vector_type(4))) float f32x4;

#define TAU_INV 2.0f

__device__ __forceinline__ short f2bf(float f) {
  unsigned u = __float_as_uint(f);
  u += 0x7fffu + ((u >> 16) & 1u);
  return (short)(u >> 16);
}
__device__ __forceinline__ float bf2f(short s) {
  return __uint_as_float(((unsigned)(unsigned short)s) << 16);
}

// ---------------- weight prep: concat-transpose to [c][k] bf16 ----------------
__global__ __launch_bounds__(256) void prep_weights(
    const float* __restrict__ w_state, const float* __restrict__ w_inj,
    const float* __restrict__ w_ga, const float* __restrict__ w_gb,
    const float* __restrict__ w_s1, const float* __restrict__ w_out,
    short* __restrict__ t_cat, short* __restrict__ t_out)
{
  int idx = blockIdx.x * 256 + threadIdx.x;
  const int NCAT = 2688 * 384;
  if (idx < NCAT) {
    int c = idx / 384, k = idx - c * 384;
    float v;
    if (c < 768)        v = w_state[k * 768 + c];
    else if (c < 1536)  v = w_inj[k * 768 + (c - 768)];
    else if (c < 1920)  v = w_ga[k * 384 + (c - 1536)];
    else if (c < 2304)  v = w_gb[k * 384 + (c - 1920)];
    else                v = w_s1[k * 384 + (c - 2304)];
    t_cat[idx] = f2bf(v);
  } else {
    int j = idx - NCAT;           // < 384*768
    int c = j / 768, k = j - c * 768;
    t_out[c * 768 + k] = f2bf(w_out[k * 384 + c]);
  }
}

// ---------------- x -> bf16 once ----------------
__global__ __launch_bounds__(256) void prep_x(
    const float* __restrict__ X, short* __restrict__ Xb)
{
  int t = blockIdx.x * 256 + threadIdx.x;
  int base = t * 8;
  float4 a = *(const float4*)(X + base);
  float4 b = *(const float4*)(X + base + 4);
  bf16x8 s;
  s[0] = f2bf(a.x); s[1] = f2bf(a.y); s[2] = f2bf(a.z); s[3] = f2bf(a.w);
  s[4] = f2bf(b.x); s[5] = f2bf(b.y); s[6] = f2bf(b.z); s[7] = f2bf(b.w);
  *(bf16x8*)(Xb + base) = s;
}

// ---------------- fused GEMM over x: all 5 projections in one pass ----------------
__global__ __launch_bounds__(256) void gemm_fused(
    const short* __restrict__ Xb, const short* __restrict__ Wt,
    const float* __restrict__ b_ga, const float* __restrict__ b_gb,
    const float* __restrict__ b_s1,
    short* __restrict__ ug, short* __restrict__ vg,
    short* __restrict__ xug, short* __restrict__ xvg,
    short* __restrict__ gag, short* __restrict__ gbg,
    short* __restrict__ s1)
{
  __shared__ short As[128 * 72];
  __shared__ short Bs[128 * 72];
  const int tid = threadIdx.x;
  const int lane = tid & 63;
  const int wv = tid >> 6;
  const int wr = wv >> 1, wc = wv & 1;
  const int m0 = blockIdx.x * 128, c0 = blockIdx.y * 128;
  const int l15 = lane & 15, l4 = lane >> 4;
  f32x4 acc[4][4] = {};
  for (int k0 = 0; k0 < 384; k0 += 64) {
    __syncthreads();
#pragma unroll
    for (int i = 0; i < 4; ++i) {
      int h = tid + i * 256;
      int m = h >> 3, kc = (h & 7) * 8;
      bf16x8 xv = *(const bf16x8*)(Xb + (m0 + m) * 384 + k0 + kc);
      *(bf16x8*)(As + m * 72 + kc) = xv;
    }
#pragma unroll
    for (int i = 0; i < 4; ++i) {
      int h = tid + i * 256;
      int c = h >> 3, kc = (h & 7) * 8;
      bf16x8 wvv = *(const bf16x8*)(Wt + (c0 + c) * 384 + k0 + kc);
      *(bf16x8*)(Bs + c * 72 + kc) = wvv;
    }
    __syncthreads();
#pragma unroll
    for (int kk = 0; kk < 2; ++kk) {
      bf16x8 af[4], bfv[4];
#pragma unroll
      for (int f = 0; f < 4; ++f) {
        af[f]  = *(const bf16x8*)(As + (wr * 64 + f * 16 + l15) * 72 + kk * 32 + l4 * 8);
        bfv[f] = *(const bf16x8*)(Bs + (wc * 64 + f * 16 + l15) * 72 + kk * 32 + l4 * 8);
      }
#pragma unroll
      for (int i = 0; i < 4; ++i)
#pragma unroll
        for (int j = 0; j < 4; ++j)
          acc[i][j] = __builtin_amdgcn_mfma_f32_16x16x32_bf16(af[i], bfv[j], acc[i][j], 0, 0, 0);
    }
  }
#pragma unroll
  for (int i = 0; i < 4; ++i) {
#pragma unroll
    for (int j = 0; j < 4; ++j) {
      const int c = c0 + wc * 64 + j * 16 + l15;
      const int mb = m0 + wr * 64 + i * 16 + l4 * 4;
      const int b = mb >> 12, n = mb & 4095;
      f32x4 v = acc[i][j];
      if (c < 1536) {               // state / inj -> grid split stores
        int cc = (c >= 768) ? (c - 768) : c;
        short* base;
        if (c < 768) base = (cc < 384) ? ug : vg;
        else         base = (cc < 384) ? xug : xvg;
        int plane = (cc >= 384) ? (cc - 384) : cc;
        short4v s;
        s[0] = f2bf(v[0]); s[1] = f2bf(v[1]); s[2] = f2bf(v[2]); s[3] = f2bf(v[3]);
        *(short4v*)(base + (b * 384 + plane) * 4096 + n) = s;
      } else if (c < 2304) {        // gates: sigmoid
        const float* bias = (c < 1920) ? b_ga : b_gb;
        short* base = (c < 1920) ? gag : gbg;
        int plane = (c < 1920) ? (c - 1536) : (c - 1920);
        float bb = bias[plane];
        short4v s;
#pragma unroll
        for (int r = 0; r < 4; ++r) {
          float t = v[r] + bb;
          s[r] = f2bf(1.f / (1.f + __expf(-t)));
        }
        *(short4v*)(base + (b * 384 + plane) * 4096 + n) = s;
      } else {                      // s1: silu, natural [m][c] layout
        int plane = c - 2304;
        float bb = b_s1[plane];
#pragma unroll
        for (int r = 0; r < 4; ++r) {
          float t = v[r] + bb;
          float sg = 1.f / (1.f + __expf(-t));
          s1[(mb + r) * 384 + plane] = f2bf(t * sg);
        }
      }
    }
  }
}

// ---------------- psi: s1 @ W_stream2 + b2, wave-per-row ----------------
__global__ __launch_bounds__(256) void psi_kernel(
    const short* __restrict__ S1, const float* __restrict__ W2,
    const float* __restrict__ b2, float* __restrict__ psi)
{
  const int lane = threadIdx.x & 63;
  const int wv = threadIdx.x >> 6;
  const int m = blockIdx.x * 4 + wv;
  float a0 = 0.f, a1 = 0.f, a2 = 0.f, a3 = 0.f;
#pragma unroll
  for (int t = 0; t < 6; ++t) {
    int k = lane + t * 64;
    float sv = bf2f(S1[m * 384 + k]);
    float4 wr = *(const float4*)(W2 + k * 4);
    a0 += sv * wr.x; a1 += sv * wr.y; a2 += sv * wr.z; a3 += sv * wr.w;
  }
  for (int off = 32; off > 0; off >>= 1) {
    a0 += __shfl_down(a0, off, 64);
    a1 += __shfl_down(a1, off, 64);
    a2 += __shfl_down(a2, off, 64);
    a3 += __shfl_down(a3, off, 64);
  }
  if (lane == 0) {
    int bb = m >> 12, n = m & 4095;
    psi[(bb * 4 + 0) * 4096 + n] = a0 + b2[0];
    psi[(bb * 4 + 1) * 4096 + n] = a1 + b2[1];
    psi[(bb * 4 + 2) * 4096 + n] = a2 + b2[2];
    psi[(bb * 4 + 3) * 4096 + n] = a3 + b2[3];
  }
}

// ---------------- routing: central diffs + softmax(5) ----------------
__global__ __launch_bounds__(256) void routing_kernel(
    const float* __restrict__ psi, const float* __restrict__ sb,
    float* __restrict__ R)
{
  const int idx = blockIdx.x * 256 + threadIdx.x;   // < 131072
  const int n = idx & 4095, bg = idx >> 12;
  const int i = n >> 6, j = n & 63;
  const float* p = psi + bg * 4096;
  float up = (i > 0)  ? p[n - 64] : 0.f;
  float dn = (i < 63) ? p[n + 64] : 0.f;
  float lf = (j > 0)  ? p[n - 1]  : 0.f;
  float rt = (j < 63) ? p[n + 1]  : 0.f;
  float vx = 0.5f * (dn - up);
  float vy = -0.5f * (rt - lf);
  float l0 = sb[bg & 3];
  float l1 = -vx * TAU_INV, l2 = vx * TAU_INV, l3 = -vy * TAU_INV, l4v = vy * TAU_INV;
  float mx = fmaxf(fmaxf(fmaxf(l0, l1), fmaxf(l2, l3)), l4v);
  float e0 = __expf(l0 - mx), e1 = __expf(l1 - mx), e2 = __expf(l2 - mx);
  float e3 = __expf(l3 - mx), e4 = __expf(l4v - mx);
  float inv = 1.f / (e0 + e1 + e2 + e3 + e4);
  const int NP = 8 * 4 * 4096;
  R[0 * NP + idx] = e0 * inv;
  R[1 * NP + idx] = e1 * inv;
  R[2 * NP + idx] = e2 * inv;
  R[3 * NP + idx] = e3 * inv;
  R[4 * NP + idx] = e4 * inv;
}

// ---------------- transport: one plane (u OR v) per block ----------------
// grid 6144: bd = blockIdx>>1, uv = blockIdx&1. Per-thread state ~90 VGPR
// fits the (512,4) cap of 128 -> no spill (r3/r4 lesson). LDS stride 65
// floats: bank = (i + 8q + c) mod 32 -> 2 lanes/bank = conflict-free (m136).
__global__ __launch_bounds__(512, 4) void transport_kernel(
    short* __restrict__ Ug, short* __restrict__ Vg,
    const short* __restrict__ Ga, const short* __restrict__ Gb,
    const short* __restrict__ Xu, const short* __restrict__ Xv,
    const float* __restrict__ R, const int* __restrict__ ksp)
{
  __shared__ float sm[64 * 65];
  const int tid = threadIdx.x;
  const int bid = blockIdx.x;
  const int uv = bid & 1;
  const int bd = bid >> 1;              // b*384 + d
  const int b = bd / 384;
  const int d = bd - b * 384;
  const int g = d / 96;
  short* __restrict__ S = uv ? Vg : Ug;
  const short* __restrict__ Xi = uv ? Xv : Xu;
  const int pbase = bd * 4096;
  const int rbase = (b * 4 + g) * 4096;
  const int NP = 8 * 4 * 4096;
  const int p0 = tid * 8;               // global pixel offset
  const int i = tid >> 3;               // row 0..63
  const int j0 = (tid & 7) * 8;         // col start
  const int base = i * 65 + j0;         // LDS index (padded stride)

  float ar0[8], ar1[8], ar2[8], ar3[8], ar4[8], bx[8];
  {
    float ga[8];
    bf16x8 t;
    t = *(const bf16x8*)(Ga + pbase + p0);
#pragma unroll
    for (int c = 0; c < 8; ++c) ga[c] = bf2f(t[c]);
    t = *(const bf16x8*)(Gb + pbase + p0);
    bf16x8 tx = *(const bf16x8*)(Xi + pbase + p0);
#pragma unroll
    for (int c = 0; c < 8; ++c) bx[c] = bf2f(t[c]) * bf2f(tx[c]);
#pragma unroll
    for (int q = 0; q < 2; ++q) {
      float4 f0 = *(const float4*)(R + 0 * NP + rbase + p0 + q * 4);
      float4 f1 = *(const float4*)(R + 1 * NP + rbase + p0 + q * 4);
      float4 f2 = *(const float4*)(R + 2 * NP + rbase + p0 + q * 4);
      float4 f3 = *(const float4*)(R + 3 * NP + rbase + p0 + q * 4);
      float4 f4 = *(const float4*)(R + 4 * NP + rbase + p0 + q * 4);
      ar0[q*4+0]=ga[q*4+0]*f0.x; ar0[q*4+1]=ga[q*4+1]*f0.y; ar0[q*4+2]=ga[q*4+2]*f0.z; ar0[q*4+3]=ga[q*4+3]*f0.w;
      ar1[q*4+0]=ga[q*4+0]*f1.x; ar1[q*4+1]=ga[q*4+1]*f1.y; ar1[q*4+2]=ga[q*4+2]*f1.z; ar1[q*4+3]=ga[q*4+3]*f1.w;
      ar2[q*4+0]=ga[q*4+0]*f2.x; ar2[q*4+1]=ga[q*4+1]*f2.y; ar2[q*4+2]=ga[q*4+2]*f2.z; ar2[q*4+3]=ga[q*4+3]*f2.w;
      ar3[q*4+0]=ga[q*4+0]*f3.x; ar3[q*4+1]=ga[q*4+1]*f3.y; ar3[q*4+2]=ga[q*4+2]*f3.z; ar3[q*4+3]=ga[q*4+3]*f3.w;
      ar4[q*4+0]=ga[q*4+0]*f4.x; ar4[q*4+1]=ga[q*4+1]*f4.y; ar4[q*4+2]=ga[q*4+2]*f4.z; ar4[q*4+3]=ga[q*4+3]*f4.w;
    }
    bf16x8 ts = *(const bf16x8*)(S + pbase + p0);
#pragma unroll
    for (int c = 0; c < 8; ++c) sm[base + c] = bf2f(ts[c]);
  }
  __syncthreads();
  const int ks = ksp[0];
  const bool hasUp = (i > 0), hasDn = (i < 63);
  for (int step = 0; step < ks; ++step) {
    float cu[8], nu[8];
#pragma unroll
    for (int c = 0; c < 8; ++c) cu[c] = sm[base + c];
    float lfe = (j0 > 0)  ? sm[base - 1] : 0.f;
    float rte = (j0 < 56) ? sm[base + 8] : 0.f;
#pragma unroll
    for (int c = 0; c < 8; ++c) {
      float up = hasUp ? sm[base - 65 + c] : 0.f;
      float dn = hasDn ? sm[base + 65 + c] : 0.f;
      float lf = (c > 0) ? cu[c - 1] : lfe;
      float rt = (c < 7) ? cu[c + 1] : rte;
      nu[c] = ar0[c]*cu[c] + ar1[c]*up + ar2[c]*dn + ar3[c]*lf + ar4[c]*rt + bx[c];
    }
    __syncthreads();
#pragma unroll
    for (int c = 0; c < 8; ++c) sm[base + c] = nu[c];
    __syncthreads();
  }
  bf16x8 os;
#pragma unroll
  for (int c = 0; c < 8; ++c) os[c] = f2bf(sm[base + c]);
  *(bf16x8*)(S + pbase + p0) = os;
}

// ---------------- final GEMM: [u|v] @ W_out + x*D_skip ----------------
__global__ __launch_bounds__(256) void gemm_final(
    const short* __restrict__ U, const short* __restrict__ V,
    const short* __restrict__ Wt, const float* __restrict__ X,
    const float* __restrict__ Dskip, float* __restrict__ out)
{
  __shared__ short As[64 * 128];   // [k][m], 16B-chunk swizzled
  __shared__ short Bs[128 * 72];   // [c][k]
  const int tid = threadIdx.x;
  const int lane = tid & 63;
  const int wv = tid >> 6, wr = wv >> 1, wc = wv & 1;
  const int m0 = blockIdx.x * 128, c0 = blockIdx.y * 128;
  const int b = m0 >> 12, n0 = m0 & 4095;
  const int l15 = lane & 15, l4 = lane >> 4;
  f32x4 acc[4][4] = {};
  for (int k0 = 0; k0 < 768; k0 += 64) {
    const short* src = (k0 < 384) ? U : V;
    const int kp = (k0 >= 384) ? (k0 - 384) : k0;
    __syncthreads();
#pragma unroll
    for (int i = 0; i < 4; ++i) {
      int h = tid + i * 256;
      int k = h >> 4, cc = h & 15;
      bf16x8 tv = *(const bf16x8*)(src + (b * 384 + kp + k) * 4096 + n0 + cc * 8);
      int ccs = cc ^ (((k >> 3) & 3) << 1);
      *(bf16x8*)(As + k * 128 + ccs * 8) = tv;
    }
#pragma unroll
    for (int i = 0; i < 4; ++i) {
      int h = tid + i * 256;
      int c = h >> 3, kc = (h & 7) * 8;
      bf16x8 wvv = *(const bf16x8*)(Wt + (c0 + c) * 768 + k0 + kc);
      *(bf16x8*)(Bs + c * 72 + kc) = wvv;
    }
    __syncthreads();
#pragma unroll
    for (int kk = 0; kk < 2; ++kk) {
      bf16x8 af[4], bfv[4];
#pragma unroll
      for (int f = 0; f < 4; ++f) {
        const int mm = wr * 64 + f * 16 + l15;
        const int chunk = mm >> 3, wi = mm & 7;
        bf16x8 av;
#pragma unroll
        for (int jj = 0; jj < 8; ++jj) {
          int k = kk * 32 + l4 * 8 + jj;
          int ccs = chunk ^ (((k >> 3) & 3) << 1);
          av[jj] = As[k * 128 + ccs * 8 + wi];
        }
        af[f] = av;
        bfv[f] = *(const bf16x8*)(Bs + (wc * 64 + f * 16 + l15) * 72 + kk * 32 + l4 * 8);
      }
#pragma unroll
      for (int i = 0; i < 4; ++i)
#pragma unroll
        for (int j = 0; j < 4; ++j)
          acc[i][j] = __builtin_amdgcn_mfma_f32_16x16x32_bf16(af[i], bfv[j], acc[i][j], 0, 0, 0);
    }
  }
#pragma unroll
  for (int i = 0; i < 4; ++i)
#pragma unroll
    for (int j = 0; j < 4; ++j) {
      const int c = c0 + wc * 64 + j * 16 + l15;
      const int mb = m0 + wr * 64 + i * 16 + l4 * 4;
      const float ds = Dskip[c];
#pragma unroll
      for (int r = 0; r < 4; ++r) {
        int idx = (mb + r) * 384 + c;
        out[idx] = acc[i][j][r] + X[idx] * ds;
      }
    }
}

extern "C" void kernel_launch(void* const* d_in, const int* in_sizes, int n_in,
                              void* d_out, int out_size, void* d_ws, size_t ws_size,
                              hipStream_t stream) {
  (void)in_sizes; (void)n_in; (void)out_size; (void)ws_size;
  const float* x       = (const float*)d_in[0];
  const float* w_s1    = (const float*)d_in[1];
  const float* b_s1    = (const float*)d_in[2];
  const float* w_s2    = (const float*)d_in[3];
  const float* b_s2    = (const float*)d_in[4];
  const float* sb      = (const float*)d_in[5];
  const float* w_ga    = (const float*)d_in[6];
  const float* b_ga    = (const float*)d_in[7];
  const float* w_gb    = (const float*)d_in[8];
  const float* b_gb    = (const float*)d_in[9];
  const float* w_inj   = (const float*)d_in[10];
  const float* w_state = (const float*)d_in[11];
  const float* w_out   = (const float*)d_in[12];
  const float* dskip   = (const float*)d_in[13];
  const int*   ksp     = (const int*)d_in[14];
  float* out = (float*)d_out;

  char* ws = (char*)d_ws;
  size_t off = 0;
  auto alloc = [&](size_t bytes) -> void* {
    void* p = ws + off;
    off += (bytes + 255) & ~(size_t)255;
    return p;
  };
  short* t_cat = (short*)alloc((size_t)2688 * 384 * 2);
  short* t_out = (short*)alloc((size_t)384 * 768 * 2);
  const size_t PL = (size_t)8 * 384 * 4096;
  short* xb  = (short*)alloc(PL * 2);
  short* ug  = (short*)alloc(PL * 2);
  short* vg  = (short*)alloc(PL * 2);
  short* xug = (short*)alloc(PL * 2);
  short* xvg = (short*)alloc(PL * 2);
  short* gag = (short*)alloc(PL * 2);
  short* gbg = (short*)alloc(PL * 2);
  short* s1  = (short*)alloc(PL * 2);
  float* psi = (float*)alloc((size_t)8 * 4 * 4096 * 4);
  float* R   = (float*)alloc((size_t)5 * 8 * 4 * 4096 * 4);

  prep_weights<<<dim3(5184), dim3(256), 0, stream>>>(
      w_state, w_inj, w_ga, w_gb, w_s1, w_out, t_cat, t_out);
  prep_x<<<dim3(6144), dim3(256), 0, stream>>>(x, xb);
  gemm_fused<<<dim3(256, 21), dim3(256), 0, stream>>>(
      xb, t_cat, b_ga, b_gb, b_s1, ug, vg, xug, xvg, gag, gbg, s1);
  psi_kernel<<<dim3(8192), dim3(256), 0, stream>>>(s1, w_s2, b_s2, psi);
  routing_kernel<<<dim3(512), dim3(256), 0, stream>>>(psi, sb, R);
  transport_kernel<<<dim3(6144), dim3(512), 0, stream>>>(ug, vg, gag, gbg, xug, xvg, R, ksp);
  gemm_final<<<dim3(256, 3), dim3(256), 0, stream>>>(ug, vg, t_out, x, dskip, out);
}

// Round 6
// 391.242 us; speedup vs baseline: 1.8139x; 1.0546x over previous
//
#include <hip/hip_runtime.h>
#include <hip/hip_bf16.h>

typedef __attribute__((ext_vector_type(8))) short bf16x8;
typedef __attribute__((ext_vector_type(4))) short short4v;
typedef __attribute__((ext_vector_type(4))) float f32x4;

#define TAU_INV 2.0f

__device__ __forceinline__ short f2bf(float f) {
  unsigned u = __float_as_uint(f);
  u += 0x7fffu + ((u >> 16) & 1u);
  return (short)(u >> 16);
}
__device__ __forceinline__ float bf2f(short s) {
  return __uint_as_float(((unsigned)(unsigned short)s) << 16);
}

// Swizzled tile image layout (shared by prep kernels and gemm_fused):
// a tile = 128 rows x 64 k-cols bf16 = 8192 shorts = 16 KB.
// image[r][s][e] (s=chunk slot 0..7, e=0..7) holds source chunk ch = s ^ (r&7):
//   element k = ktile*64 + ((s ^ (r&7))<<3) + e  of row r.
// global_load_lds writes the image linearly (lane*16B); fragment reads use
// slot = ch ^ (r&7) -> 2 lanes/bank = conflict-free (m136: 2-way is free).

// ---------------- weight prep: concat-transpose into swizzled tile images ----------------
// t_cat: 21 c-tiles x 6 k-tiles x 8192 shorts.
// cols 0..767 = W_state, 768..1535 = W_inj, 1536..1919 = W_ga,
// 1920..2303 = W_gb, 2304..2687 = W_s1.   t_out[384][768] = W_out^T (unchanged).
__global__ __launch_bounds__(256) void prep_weights(
    const float* __restrict__ w_state, const float* __restrict__ w_inj,
    const float* __restrict__ w_ga, const float* __restrict__ w_gb,
    const float* __restrict__ w_s1, const float* __restrict__ w_out,
    short* __restrict__ t_cat, short* __restrict__ t_out)
{
  int idx = blockIdx.x * 256 + threadIdx.x;
  const int NCAT = 21 * 6 * 8192;      // 1,032,192
  if (idx < NCAT) {
    int tile = idx >> 13;
    int o = idx & 8191;
    int ct = tile / 6, kt = tile - ct * 6;
    int r = o >> 6;
    int s = (o >> 3) & 7;
    int e = o & 7;
    int c = ct * 128 + r;
    int k = kt * 64 + ((s ^ (r & 7)) << 3) + e;
    float v;
    if (c < 768)        v = w_state[k * 768 + c];
    else if (c < 1536)  v = w_inj[k * 768 + (c - 768)];
    else if (c < 1920)  v = w_ga[k * 384 + (c - 1536)];
    else if (c < 2304)  v = w_gb[k * 384 + (c - 1920)];
    else                v = w_s1[k * 384 + (c - 2304)];
    t_cat[idx] = f2bf(v);
  } else {
    int j = idx - NCAT;                // < 384*768
    int c = j / 768, k = j - c * 768;
    t_out[c * 768 + k] = f2bf(w_out[k * 384 + c]);
  }
}

// ---------------- x -> bf16 swizzled tile images ----------------
// XbT: 256 m-tiles x 6 k-tiles x 8192 shorts. One 8-elem chunk per thread.
__global__ __launch_bounds__(256) void prep_x(
    const float* __restrict__ X, short* __restrict__ XbT)
{
  int t = blockIdx.x * 256 + threadIdx.x;   // chunk id, < 1,572,864
  int tile = t >> 10;
  int o = t & 1023;
  int mt = tile / 6, kt = tile - mt * 6;
  int r = o >> 3, s = o & 7;
  int m = mt * 128 + r;
  int k = kt * 64 + ((s ^ (r & 7)) << 3);
  const float* src = X + m * 384 + k;
  float4 a = *(const float4*)(src);
  float4 b = *(const float4*)(src + 4);
  bf16x8 sv;
  sv[0] = f2bf(a.x); sv[1] = f2bf(a.y); sv[2] = f2bf(a.z); sv[3] = f2bf(a.w);
  sv[4] = f2bf(b.x); sv[5] = f2bf(b.y); sv[6] = f2bf(b.z); sv[7] = f2bf(b.w);
  *(bf16x8*)(XbT + (size_t)t * 8) = sv;
}

// ---------------- fused GEMM over x: all 5 projections, global_load_lds staging ----------------
__global__ __launch_bounds__(256) void gemm_fused(
    const short* __restrict__ XbT, const short* __restrict__ WtT,
    const float* __restrict__ b_ga, const float* __restrict__ b_gb,
    const float* __restrict__ b_s1,
    short* __restrict__ ug, short* __restrict__ vg,
    short* __restrict__ xug, short* __restrict__ xvg,
    short* __restrict__ gag, short* __restrict__ gbg,
    short* __restrict__ s1)
{
  __shared__ __align__(16) short As[8192];
  __shared__ __align__(16) short Bs[8192];
  const int tid = threadIdx.x;
  const int ln = tid & 63;
  const int wv = tid >> 6;
  const int wr = wv >> 1, wc = wv & 1;
  const int mt = blockIdx.x, ct = blockIdx.y;
  const int l15 = ln & 15, l4 = ln >> 4;
  const int lsw = l15 & 7;
  f32x4 acc[4][4] = {};
  const short* aSrc = XbT + (size_t)(mt * 6) * 8192 + wv * 2048 + ln * 8;
  const short* bSrc = WtT + (size_t)(ct * 6) * 8192 + wv * 2048 + ln * 8;
  for (int kt = 0; kt < 6; ++kt) {
#pragma unroll
    for (int i = 0; i < 4; ++i) {
      __builtin_amdgcn_global_load_lds(
          (const __attribute__((address_space(1))) void*)(aSrc + i * 512),
          (__attribute__((address_space(3))) void*)(As + (wv * 4 + i) * 512),
          16, 0, 0);
      __builtin_amdgcn_global_load_lds(
          (const __attribute__((address_space(1))) void*)(bSrc + i * 512),
          (__attribute__((address_space(3))) void*)(Bs + (wv * 4 + i) * 512),
          16, 0, 0);
    }
    aSrc += 8192; bSrc += 8192;
    __syncthreads();
#pragma unroll
    for (int kk = 0; kk < 2; ++kk) {
      bf16x8 af[4], bfv[4];
#pragma unroll
      for (int f = 0; f < 4; ++f) {
        const int ra = wr * 64 + f * 16 + l15;
        const int rb = wc * 64 + f * 16 + l15;
        const int sl = (((kk << 2) | l4) ^ lsw) << 3;
        af[f]  = *(const bf16x8*)(As + ra * 64 + sl);
        bfv[f] = *(const bf16x8*)(Bs + rb * 64 + sl);
      }
#pragma unroll
      for (int i = 0; i < 4; ++i)
#pragma unroll
        for (int j = 0; j < 4; ++j)
          acc[i][j] = __builtin_amdgcn_mfma_f32_16x16x32_bf16(af[i], bfv[j], acc[i][j], 0, 0, 0);
    }
    __syncthreads();
  }
  const int m0 = mt * 128, c0 = ct * 128;
#pragma unroll
  for (int i = 0; i < 4; ++i) {
#pragma unroll
    for (int j = 0; j < 4; ++j) {
      const int c = c0 + wc * 64 + j * 16 + l15;
      const int mb = m0 + wr * 64 + i * 16 + l4 * 4;
      const int b = mb >> 12, n = mb & 4095;
      f32x4 v = acc[i][j];
      if (c < 1536) {               // state / inj -> grid split stores
        int cc = (c >= 768) ? (c - 768) : c;
        short* base;
        if (c < 768) base = (cc < 384) ? ug : vg;
        else         base = (cc < 384) ? xug : xvg;
        int plane = (cc >= 384) ? (cc - 384) : cc;
        short4v s;
        s[0] = f2bf(v[0]); s[1] = f2bf(v[1]); s[2] = f2bf(v[2]); s[3] = f2bf(v[3]);
        *(short4v*)(base + (b * 384 + plane) * 4096 + n) = s;
      } else if (c < 2304) {        // gates: sigmoid
        const float* bias = (c < 1920) ? b_ga : b_gb;
        short* base = (c < 1920) ? gag : gbg;
        int plane = (c < 1920) ? (c - 1536) : (c - 1920);
        float bb = bias[plane];
        short4v s;
#pragma unroll
        for (int r = 0; r < 4; ++r) {
          float t = v[r] + bb;
          s[r] = f2bf(1.f / (1.f + __expf(-t)));
        }
        *(short4v*)(base + (b * 384 + plane) * 4096 + n) = s;
      } else {                      // s1: silu, natural [m][c] layout
        int plane = c - 2304;
        float bb = b_s1[plane];
#pragma unroll
        for (int r = 0; r < 4; ++r) {
          float t = v[r] + bb;
          float sg = 1.f / (1.f + __expf(-t));
          s1[(mb + r) * 384 + plane] = f2bf(t * sg);
        }
      }
    }
  }
}

// ---------------- psi: s1 @ W_stream2 + b2, wave-per-row ----------------
__global__ __launch_bounds__(256) void psi_kernel(
    const short* __restrict__ S1, const float* __restrict__ W2,
    const float* __restrict__ b2, float* __restrict__ psi)
{
  const int lane = threadIdx.x & 63;
  const int wv = threadIdx.x >> 6;
  const int m = blockIdx.x * 4 + wv;
  float a0 = 0.f, a1 = 0.f, a2 = 0.f, a3 = 0.f;
#pragma unroll
  for (int t = 0; t < 6; ++t) {
    int k = lane + t * 64;
    float sv = bf2f(S1[m * 384 + k]);
    float4 wr = *(const float4*)(W2 + k * 4);
    a0 += sv * wr.x; a1 += sv * wr.y; a2 += sv * wr.z; a3 += sv * wr.w;
  }
  for (int off = 32; off > 0; off >>= 1) {
    a0 += __shfl_down(a0, off, 64);
    a1 += __shfl_down(a1, off, 64);
    a2 += __shfl_down(a2, off, 64);
    a3 += __shfl_down(a3, off, 64);
  }
  if (lane == 0) {
    int bb = m >> 12, n = m & 4095;
    psi[(bb * 4 + 0) * 4096 + n] = a0 + b2[0];
    psi[(bb * 4 + 1) * 4096 + n] = a1 + b2[1];
    psi[(bb * 4 + 2) * 4096 + n] = a2 + b2[2];
    psi[(bb * 4 + 3) * 4096 + n] = a3 + b2[3];
  }
}

// ---------------- routing: central diffs + softmax(5) ----------------
__global__ __launch_bounds__(256) void routing_kernel(
    const float* __restrict__ psi, const float* __restrict__ sb,
    float* __restrict__ R)
{
  const int idx = blockIdx.x * 256 + threadIdx.x;   // < 131072
  const int n = idx & 4095, bg = idx >> 12;
  const int i = n >> 6, j = n & 63;
  const float* p = psi + bg * 4096;
  float up = (i > 0)  ? p[n - 64] : 0.f;
  float dn = (i < 63) ? p[n + 64] : 0.f;
  float lf = (j > 0)  ? p[n - 1]  : 0.f;
  float rt = (j < 63) ? p[n + 1]  : 0.f;
  float vx = 0.5f * (dn - up);
  float vy = -0.5f * (rt - lf);
  float l0 = sb[bg & 3];
  float l1 = -vx * TAU_INV, l2 = vx * TAU_INV, l3 = -vy * TAU_INV, l4v = vy * TAU_INV;
  float mx = fmaxf(fmaxf(fmaxf(l0, l1), fmaxf(l2, l3)), l4v);
  float e0 = __expf(l0 - mx), e1 = __expf(l1 - mx), e2 = __expf(l2 - mx);
  float e3 = __expf(l3 - mx), e4 = __expf(l4v - mx);
  float inv = 1.f / (e0 + e1 + e2 + e3 + e4);
  const int NP = 8 * 4 * 4096;
  R[0 * NP + idx] = e0 * inv;
  R[1 * NP + idx] = e1 * inv;
  R[2 * NP + idx] = e2 * inv;
  R[3 * NP + idx] = e3 * inv;
  R[4 * NP + idx] = e4 * inv;
}

// ---------------- transport: one plane (u OR v) per block ----------------
__global__ __launch_bounds__(512, 4) void transport_kernel(
    short* __restrict__ Ug, short* __restrict__ Vg,
    const short* __restrict__ Ga, const short* __restrict__ Gb,
    const short* __restrict__ Xu, const short* __restrict__ Xv,
    const float* __restrict__ R, const int* __restrict__ ksp)
{
  __shared__ float sm[64 * 65];
  const int tid = threadIdx.x;
  const int bid = blockIdx.x;
  const int uv = bid & 1;
  const int bd = bid >> 1;              // b*384 + d
  const int b = bd / 384;
  const int d = bd - b * 384;
  const int g = d / 96;
  short* __restrict__ S = uv ? Vg : Ug;
  const short* __restrict__ Xi = uv ? Xv : Xu;
  const int pbase = bd * 4096;
  const int rbase = (b * 4 + g) * 4096;
  const int NP = 8 * 4 * 4096;
  const int p0 = tid * 8;               // global pixel offset
  const int i = tid >> 3;               // row 0..63
  const int j0 = (tid & 7) * 8;         // col start
  const int base = i * 65 + j0;         // LDS index (padded stride)

  float ar0[8], ar1[8], ar2[8], ar3[8], ar4[8], bx[8];
  {
    float ga[8];
    bf16x8 t;
    t = *(const bf16x8*)(Ga + pbase + p0);
#pragma unroll
    for (int c = 0; c < 8; ++c) ga[c] = bf2f(t[c]);
    t = *(const bf16x8*)(Gb + pbase + p0);
    bf16x8 tx = *(const bf16x8*)(Xi + pbase + p0);
#pragma unroll
    for (int c = 0; c < 8; ++c) bx[c] = bf2f(t[c]) * bf2f(tx[c]);
#pragma unroll
    for (int q = 0; q < 2; ++q) {
      float4 f0 = *(const float4*)(R + 0 * NP + rbase + p0 + q * 4);
      float4 f1 = *(const float4*)(R + 1 * NP + rbase + p0 + q * 4);
      float4 f2 = *(const float4*)(R + 2 * NP + rbase + p0 + q * 4);
      float4 f3 = *(const float4*)(R + 3 * NP + rbase + p0 + q * 4);
      float4 f4 = *(const float4*)(R + 4 * NP + rbase + p0 + q * 4);
      ar0[q*4+0]=ga[q*4+0]*f0.x; ar0[q*4+1]=ga[q*4+1]*f0.y; ar0[q*4+2]=ga[q*4+2]*f0.z; ar0[q*4+3]=ga[q*4+3]*f0.w;
      ar1[q*4+0]=ga[q*4+0]*f1.x; ar1[q*4+1]=ga[q*4+1]*f1.y; ar1[q*4+2]=ga[q*4+2]*f1.z; ar1[q*4+3]=ga[q*4+3]*f1.w;
      ar2[q*4+0]=ga[q*4+0]*f2.x; ar2[q*4+1]=ga[q*4+1]*f2.y; ar2[q*4+2]=ga[q*4+2]*f2.z; ar2[q*4+3]=ga[q*4+3]*f2.w;
      ar3[q*4+0]=ga[q*4+0]*f3.x; ar3[q*4+1]=ga[q*4+1]*f3.y; ar3[q*4+2]=ga[q*4+2]*f3.z; ar3[q*4+3]=ga[q*4+3]*f3.w;
      ar4[q*4+0]=ga[q*4+0]*f4.x; ar4[q*4+1]=ga[q*4+1]*f4.y; ar4[q*4+2]=ga[q*4+2]*f4.z; ar4[q*4+3]=ga[q*4+3]*f4.w;
    }
    bf16x8 ts = *(const bf16x8*)(S + pbase + p0);
#pragma unroll
    for (int c = 0; c < 8; ++c) sm[base + c] = bf2f(ts[c]);
  }
  __syncthreads();
  const int ks = ksp[0];
  const bool hasUp = (i > 0), hasDn = (i < 63);
  for (int step = 0; step < ks; ++step) {
    float cu[8], nu[8];
#pragma unroll
    for (int c = 0; c < 8; ++c) cu[c] = sm[base + c];
    float lfe = (j0 > 0)  ? sm[base - 1] : 0.f;
    float rte = (j0 < 56) ? sm[base + 8] : 0.f;
#pragma unroll
    for (int c = 0; c < 8; ++c) {
      float up = hasUp ? sm[base - 65 + c] : 0.f;
      float dn = hasDn ? sm[base + 65 + c] : 0.f;
      float lf = (c > 0) ? cu[c - 1] : lfe;
      float rt = (c < 7) ? cu[c + 1] : rte;
      nu[c] = ar0[c]*cu[c] + ar1[c]*up + ar2[c]*dn + ar3[c]*lf + ar4[c]*rt + bx[c];
    }
    __syncthreads();
#pragma unroll
    for (int c = 0; c < 8; ++c) sm[base + c] = nu[c];
    __syncthreads();
  }
  bf16x8 os;
#pragma unroll
  for (int c = 0; c < 8; ++c) os[c] = f2bf(sm[base + c]);
  *(bf16x8*)(S + pbase + p0) = os;
}

// ---------------- final GEMM: [u|v] @ W_out + x*D_skip ----------------
__global__ __launch_bounds__(256) void gemm_final(
    const short* __restrict__ U, const short* __restrict__ V,
    const short* __restrict__ Wt, const float* __restrict__ X,
    const float* __restrict__ Dskip, float* __restrict__ out)
{
  __shared__ short As[64 * 128];   // [k][m], 16B-chunk swizzled
  __shared__ short Bs[128 * 72];   // [c][k]
  const int tid = threadIdx.x;
  const int lane = tid & 63;
  const int wv = tid >> 6, wr = wv >> 1, wc = wv & 1;
  const int m0 = blockIdx.x * 128, c0 = blockIdx.y * 128;
  const int b = m0 >> 12, n0 = m0 & 4095;
  const int l15 = lane & 15, l4 = lane >> 4;
  f32x4 acc[4][4] = {};
  for (int k0 = 0; k0 < 768; k0 += 64) {
    const short* src = (k0 < 384) ? U : V;
    const int kp = (k0 >= 384) ? (k0 - 384) : k0;
    __syncthreads();
#pragma unroll
    for (int i = 0; i < 4; ++i) {
      int h = tid + i * 256;
      int k = h >> 4, cc = h & 15;
      bf16x8 tv = *(const bf16x8*)(src + (b * 384 + kp + k) * 4096 + n0 + cc * 8);
      int ccs = cc ^ (((k >> 3) & 3) << 1);
      *(bf16x8*)(As + k * 128 + ccs * 8) = tv;
    }
#pragma unroll
    for (int i = 0; i < 4; ++i) {
      int h = tid + i * 256;
      int c = h >> 3, kc = (h & 7) * 8;
      bf16x8 wvv = *(const bf16x8*)(Wt + (c0 + c) * 768 + k0 + kc);
      *(bf16x8*)(Bs + c * 72 + kc) = wvv;
    }
    __syncthreads();
#pragma unroll
    for (int kk = 0; kk < 2; ++kk) {
      bf16x8 af[4], bfv[4];
#pragma unroll
      for (int f = 0; f < 4; ++f) {
        const int mm = wr * 64 + f * 16 + l15;
        const int chunk = mm >> 3, wi = mm & 7;
        bf16x8 av;
#pragma unroll
        for (int jj = 0; jj < 8; ++jj) {
          int k = kk * 32 + l4 * 8 + jj;
          int ccs = chunk ^ (((k >> 3) & 3) << 1);
          av[jj] = As[k * 128 + ccs * 8 + wi];
        }
        af[f] = av;
        bfv[f] = *(const bf16x8*)(Bs + (wc * 64 + f * 16 + l15) * 72 + kk * 32 + l4 * 8);
      }
#pragma unroll
      for (int i = 0; i < 4; ++i)
#pragma unroll
        for (int j = 0; j < 4; ++j)
          acc[i][j] = __builtin_amdgcn_mfma_f32_16x16x32_bf16(af[i], bfv[j], acc[i][j], 0, 0, 0);
    }
  }
#pragma unroll
  for (int i = 0; i < 4; ++i)
#pragma unroll
    for (int j = 0; j < 4; ++j) {
      const int c = c0 + wc * 64 + j * 16 + l15;
      const int mb = m0 + wr * 64 + i * 16 + l4 * 4;
      const float ds = Dskip[c];
#pragma unroll
      for (int r = 0; r < 4; ++r) {
        int idx = (mb + r) * 384 + c;
        out[idx] = acc[i][j][r] + X[idx] * ds;
      }
    }
}

extern "C" void kernel_launch(void* const* d_in, const int* in_sizes, int n_in,
                              void* d_out, int out_size, void* d_ws, size_t ws_size,
                              hipStream_t stream) {
  (void)in_sizes; (void)n_in; (void)out_size; (void)ws_size;
  const float* x       = (const float*)d_in[0];
  const float* w_s1    = (const float*)d_in[1];
  const float* b_s1    = (const float*)d_in[2];
  const float* w_s2    = (const float*)d_in[3];
  const float* b_s2    = (const float*)d_in[4];
  const float* sb      = (const float*)d_in[5];
  const float* w_ga    = (const float*)d_in[6];
  const float* b_ga    = (const float*)d_in[7];
  const float* w_gb    = (const float*)d_in[8];
  const float* b_gb    = (const float*)d_in[9];
  const float* w_inj   = (const float*)d_in[10];
  const float* w_state = (const float*)d_in[11];
  const float* w_out   = (const float*)d_in[12];
  const float* dskip   = (const float*)d_in[13];
  const int*   ksp     = (const int*)d_in[14];
  float* out = (float*)d_out;

  char* ws = (char*)d_ws;
  size_t off = 0;
  auto alloc = [&](size_t bytes) -> void* {
    void* p = ws + off;
    off += (bytes + 255) & ~(size_t)255;
    return p;
  };
  short* t_cat = (short*)alloc((size_t)21 * 6 * 8192 * 2);
  short* t_out = (short*)alloc((size_t)384 * 768 * 2);
  const size_t PL = (size_t)8 * 384 * 4096;
  short* xbt = (short*)alloc(PL * 2);      // 256 m-tiles x 6 k-tiles x 8192
  short* ug  = (short*)alloc(PL * 2);
  short* vg  = (short*)alloc(PL * 2);
  short* xug = (short*)alloc(PL * 2);
  short* xvg = (short*)alloc(PL * 2);
  short* gag = (short*)alloc(PL * 2);
  short* gbg = (short*)alloc(PL * 2);
  short* s1  = (short*)alloc(PL * 2);
  float* psi = (float*)alloc((size_t)8 * 4 * 4096 * 4);
  float* R   = (float*)alloc((size_t)5 * 8 * 4 * 4096 * 4);

  prep_weights<<<dim3(5184), dim3(256), 0, stream>>>(
      w_state, w_inj, w_ga, w_gb, w_s1, w_out, t_cat, t_out);
  prep_x<<<dim3(6144), dim3(256), 0, stream>>>(x, xbt);
  gemm_fused<<<dim3(256, 21), dim3(256), 0, stream>>>(
      xbt, t_cat, b_ga, b_gb, b_s1, ug, vg, xug, xvg, gag, gbg, s1);
  psi_kernel<<<dim3(8192), dim3(256), 0, stream>>>(s1, w_s2, b_s2, psi);
  routing_kernel<<<dim3(512), dim3(256), 0, stream>>>(psi, sb, R);
  transport_kernel<<<dim3(6144), dim3(512), 0, stream>>>(ug, vg, gag, gbg, xug, xvg, R, ksp);
  gemm_final<<<dim3(256, 3), dim3(256), 0, stream>>>(ug, vg, t_out, x, dskip, out);
}